// Round 20
// baseline (255.412 us; speedup 1.0000x reference)
//
#include <hip/hip_runtime.h>
#include <math.h>

// Problem constants (B,C,H,W) = (8,128,256,256), Ch = 64
constexpr int Bn = 8, Cn = 128, ChN = 64, Hn = 256, Wn = 256;
constexpr long long HWn  = (long long)Hn * Wn;   // 65536
constexpr long long CHWn = (long long)Cn * HWn;  // 8388608

typedef short  s16x8  __attribute__((ext_vector_type(8)));
typedef __bf16 bf16x8 __attribute__((ext_vector_type(8)));
typedef float  f32x4  __attribute__((ext_vector_type(4)));

static __device__ __forceinline__ unsigned short f2bf(float f) {
    union { float f; unsigned u; } v; v.f = f;
    unsigned r = (v.u + 0x7FFFu + ((v.u >> 16) & 1u)) >> 16;
    return (unsigned short)r;
}
static __device__ __forceinline__ bf16x8 tobf(s16x8 s) {
    bf16x8 r; __builtin_memcpy(&r, &s, 16); return r;
}

// Prep: pack w1 (64x128 f32) into MFMA A-fragments (bf16), and transpose w2.
__global__ void prep(const float* __restrict__ w1, const float* __restrict__ w2,
                     uint4* __restrict__ af, float* __restrict__ w2t) {
    int idx = blockIdx.x * 256 + threadIdx.x;
    if (idx < 1024) {
        int lane = idx & 63, kb = (idx >> 6) & 3, ot = idx >> 8;
        int row   = ot * 16 + (lane & 15);
        int kbase = kb * 32 + ((lane >> 4) & 3) * 8;
        const float* src = w1 + row * Cn + kbase;
        unsigned short b[8];
        #pragma unroll
        for (int t = 0; t < 8; ++t) b[t] = f2bf(src[t]);
        uint4 r;
        r.x = (unsigned)b[0] | ((unsigned)b[1] << 16);
        r.y = (unsigned)b[2] | ((unsigned)b[3] << 16);
        r.z = (unsigned)b[4] | ((unsigned)b[5] << 16);
        r.w = (unsigned)b[6] | ((unsigned)b[7] << 16);
        af[idx] = r;
    } else if (idx < 1024 + ChN * 4) {
        int t = idx - 1024;               // t = o*4 + k
        w2t[t] = w2[(t & 3) * ChN + (t >> 2)];
    }
}

__device__ __forceinline__ float softplus_f(float x) {
    return fmaxf(x, 0.0f) + log1pf(expf(-fabsf(x)));
}

// ============================ Kernel A: w-field ============================
// (unchanged from round 19) Chunk-pair per wave-iteration, float2 loads,
// packed output wpk[((b*Hn+i)*4+dir)*Wn + j].
__global__ __launch_bounds__(256) void wfield(
    const float* __restrict__ wi,
    const uint4* __restrict__ af,
    const float* __restrict__ w2t,
    const float* __restrict__ b1,
    const float* __restrict__ b2,
    float* __restrict__ wpk)
{
    const int tid  = threadIdx.x;
    const int wv   = tid >> 6;
    const int lane = tid & 63;
    const int l15  = lane & 15;
    const int lg   = lane >> 4;

    const int wid = blockIdx.x * 4 + wv;       // 0..8191

    for (int q = 0; q < 2; ++q) {
        const int grp = wid * 2 + q;           // 0..16383 (32-px group)
        const int p0  = grp * 32;              // first pixel (b-i-j linear)
        const int bb  = p0 >> 16;              // batch
        const int rem = p0 & (int)(HWn - 1);   // i*Wn + j (row-aligned by 32)

        const float* wip = wi + (size_t)bb * CHWn + rem + 2 * l15;

        float2 xb[32];
        #pragma unroll
        for (int kb = 0; kb < 4; ++kb)
            #pragma unroll
            for (int t = 0; t < 8; ++t)
                xb[kb * 8 + t] = *(const float2*)(wip + (size_t)(kb * 32 + lg * 8 + t) * HWn);

        f32x4 accA[4], accB[4];
        #pragma unroll
        for (int ot = 0; ot < 4; ++ot) {
            f32x4 b1v = *(const f32x4*)(b1 + ot * 16 + lg * 4);  // b1 in C
            accA[ot] = b1v;
            accB[ot] = b1v;
        }

        #pragma unroll
        for (int kb = 0; kb < 4; ++kb) {
            s16x8 bsA, bsB;
            #pragma unroll
            for (int t = 0; t < 8; ++t) {
                bsA[t] = (short)f2bf(xb[kb * 8 + t].x);
                bsB[t] = (short)f2bf(xb[kb * 8 + t].y);
            }
            bf16x8 bfA = tobf(bsA), bfB = tobf(bsB);
            #pragma unroll
            for (int ot = 0; ot < 4; ++ot) {
                s16x8 as = ((const s16x8*)af)[(ot * 4 + kb) * 64 + lane];
                bf16x8 av = tobf(as);
                accA[ot] = __builtin_amdgcn_mfma_f32_16x16x32_bf16(av, bfA, accA[ot], 0, 0, 0);
                accB[ot] = __builtin_amdgcn_mfma_f32_16x16x32_bf16(av, bfB, accB[ot], 0, 0, 0);
            }
        }

        float a0A = 0.f, a1A = 0.f, a2A = 0.f, a3A = 0.f;
        float a0B = 0.f, a1B = 0.f, a2B = 0.f, a3B = 0.f;
        #pragma unroll
        for (int ot = 0; ot < 4; ++ot) {
            #pragma unroll
            for (int r = 0; r < 4; ++r) {
                int o = ot * 16 + lg * 4 + r;
                const float4 w4v = ((const float4*)w2t)[o];
                float hA = fmaxf(accA[ot][r], 0.f);
                float hB = fmaxf(accB[ot][r], 0.f);
                a0A = fmaf(w4v.x, hA, a0A); a0B = fmaf(w4v.x, hB, a0B);
                a1A = fmaf(w4v.y, hA, a1A); a1B = fmaf(w4v.y, hB, a1B);
                a2A = fmaf(w4v.z, hA, a2A); a2B = fmaf(w4v.z, hB, a2B);
                a3A = fmaf(w4v.w, hA, a3A); a3B = fmaf(w4v.w, hB, a3B);
            }
        }
        a0A += __shfl_xor(a0A, 16); a0A += __shfl_xor(a0A, 32);
        a1A += __shfl_xor(a1A, 16); a1A += __shfl_xor(a1A, 32);
        a2A += __shfl_xor(a2A, 16); a2A += __shfl_xor(a2A, 32);
        a3A += __shfl_xor(a3A, 16); a3A += __shfl_xor(a3A, 32);
        a0B += __shfl_xor(a0B, 16); a0B += __shfl_xor(a0B, 32);
        a1B += __shfl_xor(a1B, 16); a1B += __shfl_xor(a1B, 32);
        a2B += __shfl_xor(a2B, 16); a2B += __shfl_xor(a2B, 32);
        a3B += __shfl_xor(a3B, 16); a3B += __shfl_xor(a3B, 32);

        if (lg == 0) {
            const int i  = (p0 >> 8) & 255;
            const int jA = (p0 & 255) + 2 * l15;
            float* wrow = wpk + ((size_t)(bb * Hn + i) * 4) * Wn;
            wrow[0 * Wn + jA] = softplus_f(a0A + b2[0]);
            wrow[1 * Wn + jA] = softplus_f(a1A + b2[1]);
            wrow[2 * Wn + jA] = softplus_f(a2A + b2[2]);
            wrow[3 * Wn + jA] = softplus_f(a3A + b2[3]);
            wrow[0 * Wn + jA + 1] = softplus_f(a0B + b2[0]);
            wrow[1 * Wn + jA + 1] = softplus_f(a1B + b2[1]);
            wrow[2 * Wn + jA + 1] = softplus_f(a2B + b2[2]);
            wrow[3 * Wn + jA + 1] = softplus_f(a3B + b2[3]);
        }
    }
}

// ============================ Kernel B: stencil ============================
// GRID-STRIDE, COPY-SHAPED: thread t handles out f32x4 index
// g = it*524288 + blk*256 + tid, 32 iterations. The whole grid sweeps u/out
// as ONE contiguous 8-MB window (m13-copy's global pattern) instead of
// per-block scattered tiles (round 12/14: hundreds of independent 1-KB
// streams per XCD-L2 -> 2.3-3 TB/s equilibrium). Row = 64 f32x4 = exactly
// one wave -> lane==j4; left/right via shuffle; w from wpk (L2/L3-resident).
__global__ __launch_bounds__(256) void stencil_gs(
    const float* __restrict__ u,
    const float* __restrict__ wpk,
    float* __restrict__ out)
{
    const int tid  = threadIdx.x;
    const int lane = tid & 63;
    const size_t base0 = (size_t)blockIdx.x * 256 + tid;   // f32x4 index
    const f32x4 z4 = {0.f, 0.f, 0.f, 0.f};

    #pragma unroll 2
    for (int it = 0; it < 32; ++it) {
        const size_t g = base0 + (size_t)it * (2048 * 256);
        const int i = (int)((g >> 6) & 255);
        const int b = (int)(g >> 21);

        const float* cp = u + g * 4;
        f32x4 ctr = *(const f32x4*)cp;
        f32x4 up4 = (i > 0)       ? *(const f32x4*)(cp - Wn) : z4;
        f32x4 dn4 = (i < Hn - 1)  ? *(const f32x4*)(cp + Wn) : z4;

        const float* wrow = wpk + (((size_t)(b * Hn + i) * 4) << 8) + 4 * lane;
        f32x4 WU = *(const f32x4*)(wrow + 0 * Wn);
        f32x4 WD = *(const f32x4*)(wrow + 1 * Wn);
        f32x4 WL = *(const f32x4*)(wrow + 2 * Wn);
        f32x4 WR = *(const f32x4*)(wrow + 3 * Wn);

        float lw = __shfl(ctr[3], lane - 1);
        float rw = __shfl(ctr[0], lane + 1);
        float lfx = (lane == 0)  ? 0.f : lw;
        float rtw = (lane == 63) ? 0.f : rw;

        f32x4 WS = (WU + WD) + (WL + WR);

        f32x4 res;
        res[0] = fmaf(WU[0], up4[0], fmaf(WD[0], dn4[0], fmaf(WL[0], lfx,    fmaf(WR[0], ctr[1], -WS[0] * ctr[0]))));
        res[1] = fmaf(WU[1], up4[1], fmaf(WD[1], dn4[1], fmaf(WL[1], ctr[0], fmaf(WR[1], ctr[2], -WS[1] * ctr[1]))));
        res[2] = fmaf(WU[2], up4[2], fmaf(WD[2], dn4[2], fmaf(WL[2], ctr[1], fmaf(WR[2], ctr[3], -WS[2] * ctr[2]))));
        res[3] = fmaf(WU[3], up4[3], fmaf(WD[3], dn4[3], fmaf(WL[3], ctr[2], fmaf(WR[3], rtw,    -WS[3] * ctr[3]))));

        *(f32x4*)(out + g * 4) = res;
    }
}

extern "C" void kernel_launch(void* const* d_in, const int* in_sizes, int n_in,
                              void* d_out, int out_size, void* d_ws, size_t ws_size,
                              hipStream_t stream) {
    const float* u  = (const float*)d_in[0];
    const float* wi = (const float*)d_in[1];
    const float* w1 = (const float*)d_in[2];
    const float* b1 = (const float*)d_in[3];
    const float* w2 = (const float*)d_in[4];
    const float* b2 = (const float*)d_in[5];
    float* out = (float*)d_out;

    uint4* af  = (uint4*)d_ws;                       // 16 KB
    float* w2t = (float*)((char*)d_ws + 16384);      // 1 KB (pad to 17408)
    float* wpk = (float*)((char*)d_ws + 17408);      // 8 MB packed w-field

    prep<<<5, 256, 0, stream>>>(w1, w2, af, w2t);
    wfield<<<2048, 256, 0, stream>>>(wi, af, w2t, b1, b2, wpk);
    stencil_gs<<<2048, 256, 0, stream>>>(u, wpk, out);
}

// Round 21
// 188.141 us; speedup vs baseline: 1.3576x; 1.3576x over previous
//
#include <hip/hip_runtime.h>
#include <math.h>

// Problem constants (B,C,H,W) = (8,128,256,256), Ch = 64
constexpr int Bn = 8, Cn = 128, ChN = 64, Hn = 256, Wn = 256;
constexpr long long HWn  = (long long)Hn * Wn;   // 65536
constexpr long long CHWn = (long long)Cn * HWn;  // 8388608

typedef short  s16x8  __attribute__((ext_vector_type(8)));
typedef __bf16 bf16x8 __attribute__((ext_vector_type(8)));
typedef float  f32x4  __attribute__((ext_vector_type(4)));

static __device__ __forceinline__ unsigned short f2bf(float f) {
    union { float f; unsigned u; } v; v.f = f;
    unsigned r = (v.u + 0x7FFFu + ((v.u >> 16) & 1u)) >> 16;
    return (unsigned short)r;
}
static __device__ __forceinline__ bf16x8 tobf(s16x8 s) {
    bf16x8 r; __builtin_memcpy(&r, &s, 16); return r;
}

// Prep: pack w1 (64x128 f32) into MFMA A-fragments (bf16), and transpose w2.
__global__ void prep(const float* __restrict__ w1, const float* __restrict__ w2,
                     uint4* __restrict__ af, float* __restrict__ w2t) {
    int idx = blockIdx.x * 256 + threadIdx.x;
    if (idx < 1024) {
        int lane = idx & 63, kb = (idx >> 6) & 3, ot = idx >> 8;
        int row   = ot * 16 + (lane & 15);
        int kbase = kb * 32 + ((lane >> 4) & 3) * 8;
        const float* src = w1 + row * Cn + kbase;
        unsigned short b[8];
        #pragma unroll
        for (int t = 0; t < 8; ++t) b[t] = f2bf(src[t]);
        uint4 r;
        r.x = (unsigned)b[0] | ((unsigned)b[1] << 16);
        r.y = (unsigned)b[2] | ((unsigned)b[3] << 16);
        r.z = (unsigned)b[4] | ((unsigned)b[5] << 16);
        r.w = (unsigned)b[6] | ((unsigned)b[7] << 16);
        af[idx] = r;
    } else if (idx < 1024 + ChN * 4) {
        int t = idx - 1024;               // t = o*4 + k
        w2t[t] = w2[(t & 3) * ChN + (t >> 2)];
    }
}

__device__ __forceinline__ float softplus_f(float x) {
    return fmaxf(x, 0.0f) + log1pf(expf(-fabsf(x)));
}

// ============================ Kernel A: w-field ============================
// Chunk-pair per wave-iteration (32 contiguous px, float2 loads = full 128-B
// line per 16-lane group per channel). q-loop UNROLLED so group q=1's load
// batch issues under q=0's MFMA/VALU phase (cross-group overlap).
// Output: packed wpk[((b*Hn+i)*4+dir)*Wn + j].
__global__ __launch_bounds__(256) void wfield(
    const float* __restrict__ wi,
    const uint4* __restrict__ af,
    const float* __restrict__ w2t,
    const float* __restrict__ b1,
    const float* __restrict__ b2,
    float* __restrict__ wpk)
{
    const int tid  = threadIdx.x;
    const int wv   = tid >> 6;
    const int lane = tid & 63;
    const int l15  = lane & 15;
    const int lg   = lane >> 4;

    const int wid = blockIdx.x * 4 + wv;       // 0..8191

    #pragma unroll
    for (int q = 0; q < 2; ++q) {
        const int grp = wid * 2 + q;           // 0..16383 (32-px group)
        const int p0  = grp * 32;              // first pixel (b-i-j linear)
        const int bb  = p0 >> 16;              // batch
        const int rem = p0 & (int)(HWn - 1);   // i*Wn + j (row-aligned by 32)

        const float* wip = wi + (size_t)bb * CHWn + rem + 2 * l15;

        // all 32 channel-strided float2 loads in flight before dependent work
        float2 xb[32];
        #pragma unroll
        for (int kb = 0; kb < 4; ++kb)
            #pragma unroll
            for (int t = 0; t < 8; ++t)
                xb[kb * 8 + t] = *(const float2*)(wip + (size_t)(kb * 32 + lg * 8 + t) * HWn);

        f32x4 accA[4], accB[4];
        #pragma unroll
        for (int ot = 0; ot < 4; ++ot) {
            f32x4 b1v = *(const f32x4*)(b1 + ot * 16 + lg * 4);  // b1 in C
            accA[ot] = b1v;
            accB[ot] = b1v;
        }

        #pragma unroll
        for (int kb = 0; kb < 4; ++kb) {
            s16x8 bsA, bsB;
            #pragma unroll
            for (int t = 0; t < 8; ++t) {
                bsA[t] = (short)f2bf(xb[kb * 8 + t].x);
                bsB[t] = (short)f2bf(xb[kb * 8 + t].y);
            }
            bf16x8 bfA = tobf(bsA), bfB = tobf(bsB);
            #pragma unroll
            for (int ot = 0; ot < 4; ++ot) {
                s16x8 as = ((const s16x8*)af)[(ot * 4 + kb) * 64 + lane];
                bf16x8 av = tobf(as);
                accA[ot] = __builtin_amdgcn_mfma_f32_16x16x32_bf16(av, bfA, accA[ot], 0, 0, 0);
                accB[ot] = __builtin_amdgcn_mfma_f32_16x16x32_bf16(av, bfB, accB[ot], 0, 0, 0);
            }
        }

        float a0A = 0.f, a1A = 0.f, a2A = 0.f, a3A = 0.f;
        float a0B = 0.f, a1B = 0.f, a2B = 0.f, a3B = 0.f;
        #pragma unroll
        for (int ot = 0; ot < 4; ++ot) {
            #pragma unroll
            for (int r = 0; r < 4; ++r) {
                int o = ot * 16 + lg * 4 + r;
                const float4 w4v = ((const float4*)w2t)[o];
                float hA = fmaxf(accA[ot][r], 0.f);
                float hB = fmaxf(accB[ot][r], 0.f);
                a0A = fmaf(w4v.x, hA, a0A); a0B = fmaf(w4v.x, hB, a0B);
                a1A = fmaf(w4v.y, hA, a1A); a1B = fmaf(w4v.y, hB, a1B);
                a2A = fmaf(w4v.z, hA, a2A); a2B = fmaf(w4v.z, hB, a2B);
                a3A = fmaf(w4v.w, hA, a3A); a3B = fmaf(w4v.w, hB, a3B);
            }
        }
        a0A += __shfl_xor(a0A, 16); a0A += __shfl_xor(a0A, 32);
        a1A += __shfl_xor(a1A, 16); a1A += __shfl_xor(a1A, 32);
        a2A += __shfl_xor(a2A, 16); a2A += __shfl_xor(a2A, 32);
        a3A += __shfl_xor(a3A, 16); a3A += __shfl_xor(a3A, 32);
        a0B += __shfl_xor(a0B, 16); a0B += __shfl_xor(a0B, 32);
        a1B += __shfl_xor(a1B, 16); a1B += __shfl_xor(a1B, 32);
        a2B += __shfl_xor(a2B, 16); a2B += __shfl_xor(a2B, 32);
        a3B += __shfl_xor(a3B, 16); a3B += __shfl_xor(a3B, 32);

        if (lg == 0) {
            const int i  = (p0 >> 8) & 255;
            const int jA = (p0 & 255) + 2 * l15;
            float* wrow = wpk + ((size_t)(bb * Hn + i) * 4) * Wn;
            wrow[0 * Wn + jA] = softplus_f(a0A + b2[0]);
            wrow[1 * Wn + jA] = softplus_f(a1A + b2[1]);
            wrow[2 * Wn + jA] = softplus_f(a2A + b2[2]);
            wrow[3 * Wn + jA] = softplus_f(a3A + b2[3]);
            wrow[0 * Wn + jA + 1] = softplus_f(a0B + b2[0]);
            wrow[1 * Wn + jA + 1] = softplus_f(a1B + b2[1]);
            wrow[2 * Wn + jA + 1] = softplus_f(a2B + b2[2]);
            wrow[3 * Wn + jA + 1] = softplus_f(a3B + b2[3]);
        }
    }
}

// ============================ Kernel B: stencil ============================
// (round-14 structure — best measured) Block = (b, 8-row strip, c-quarter);
// strip's packed w (32 KB) staged to LDS once; per channel: 10 contiguous
// u-rows upfront, 8 rows computed, 8 KB stored.
// Grid = 8 b x 32 strips x 4 cq = 1024; blk&7 = batch = XCD partition.
__global__ __launch_bounds__(256) void stencil5(
    const float* __restrict__ u,
    const float* __restrict__ wpk,
    float* __restrict__ out)
{
    const int bb    = blockIdx.x & 7;
    const int rest  = blockIdx.x >> 3;      // 0..127
    const int strip = rest & 31;            // 8-row strip
    const int cq    = rest >> 5;            // 0..3
    const int tid   = threadIdx.x;
    const int wv    = tid >> 6;
    const int lane  = tid & 63;

    const int i0 = strip * 8;
    const int c0 = cq * 32 + wv * 8;
    const int j4 = lane * 4;

    __shared__ float wlds[8 * 4 * 256];     // 32 KB: [r][dir][j]

    // stage: strip's packed w is 32 KB contiguous
    const float* wsrc = wpk + ((size_t)(bb * Hn + i0) * 4) * Wn;
    #pragma unroll
    for (int k = 0; k < 8; ++k) {
        f32x4 v = *(const f32x4*)(wsrc + (size_t)(k * 256 + tid) * 4);
        *(f32x4*)(wlds + (k * 256 + tid) * 4) = v;
    }
    __syncthreads();

    const float4 z4 = {0.f, 0.f, 0.f, 0.f};

    #pragma unroll 2
    for (int cc = 0; cc < 8; ++cc) {
        const int c = c0 + cc;
        const size_t plane = ((size_t)bb * Cn + c) * HWn;
        const float* up0 = u   + plane + j4;
        float*       po  = out + plane + j4;

        // 10 u-rows upfront: i0-1 .. i0+8 (boundary -> 0)
        float4 R[10];
        #pragma unroll
        for (int k = 0; k < 10; ++k) {
            const int i = i0 - 1 + k;
            R[k] = (i >= 0 && i < Hn) ? *(const float4*)(up0 + (size_t)i * Wn) : z4;
        }

        #pragma unroll
        for (int r = 0; r < 8; ++r) {
            float4 ctr = R[r + 1], up4 = R[r], dn4 = R[r + 2];
            const f32x4* wrow = (const f32x4*)(wlds + (size_t)(r * 4) * 256);
            f32x4 WU = wrow[0 * 64 + lane];
            f32x4 WD = wrow[1 * 64 + lane];
            f32x4 WL = wrow[2 * 64 + lane];
            f32x4 WR = wrow[3 * 64 + lane];

            float lw = __shfl(ctr.w, lane - 1);
            float rw = __shfl(ctr.x, lane + 1);
            float lfx = (lane == 0)  ? 0.f : lw;
            float rtw = (lane == 63) ? 0.f : rw;

            f32x4 WS = (WU + WD) + (WL + WR);

            f32x4 res;
            res[0] = fmaf(WU[0], up4.x, fmaf(WD[0], dn4.x, fmaf(WL[0], lfx,   fmaf(WR[0], ctr.y, -WS[0] * ctr.x))));
            res[1] = fmaf(WU[1], up4.y, fmaf(WD[1], dn4.y, fmaf(WL[1], ctr.x, fmaf(WR[1], ctr.z, -WS[1] * ctr.y))));
            res[2] = fmaf(WU[2], up4.z, fmaf(WD[2], dn4.z, fmaf(WL[2], ctr.y, fmaf(WR[2], ctr.w, -WS[2] * ctr.z))));
            res[3] = fmaf(WU[3], up4.w, fmaf(WD[3], dn4.w, fmaf(WL[3], ctr.z, fmaf(WR[3], rtw,   -WS[3] * ctr.w))));

            *(f32x4*)(po + (size_t)(i0 + r) * Wn) = res;
        }
    }
}

extern "C" void kernel_launch(void* const* d_in, const int* in_sizes, int n_in,
                              void* d_out, int out_size, void* d_ws, size_t ws_size,
                              hipStream_t stream) {
    const float* u  = (const float*)d_in[0];
    const float* wi = (const float*)d_in[1];
    const float* w1 = (const float*)d_in[2];
    const float* b1 = (const float*)d_in[3];
    const float* w2 = (const float*)d_in[4];
    const float* b2 = (const float*)d_in[5];
    float* out = (float*)d_out;

    uint4* af  = (uint4*)d_ws;                       // 16 KB
    float* w2t = (float*)((char*)d_ws + 16384);      // 1 KB (pad to 17408)
    float* wpk = (float*)((char*)d_ws + 17408);      // 8 MB packed w-field

    prep<<<5, 256, 0, stream>>>(w1, w2, af, w2t);
    wfield<<<2048, 256, 0, stream>>>(wi, af, w2t, b1, b2, wpk);
    stencil5<<<1024, 256, 0, stream>>>(u, wpk, out);
}